// Round 11
// baseline (2960.496 us; speedup 1.0000x reference)
//
#include <hip/hip_runtime.h>
#include <math.h>

// RITS recurrent model, MFMA bf16, r9 structure + 2 blocks/CU:
// 512 blocks x 512 threads (8 waves); each block owns 8 batch rows (MFMA tiles
// padded to 16 rows; padding rows are exact zeros: h_r masked to 0 for rows>=8,
// xm_s zero-initialized -> e rows>=8 = 0, m rows>=8 = 0). Two independent
// blocks per CU (VGPR=128 @ __launch_bounds__(512,4)) overlap each other's
// barrier stalls - the latency hiding r5 could not get (shared barrier group).
// Wave w owns jh cols [16w,16w+16). MFMA 16x16x32 lane layout (m89-verified):
//   cidx=l&15 (A row / D col), gidx=l>>4; D: row=4*gidx+v, col=cidx.
//   A row r contributes only to D row r -> padding rows are contained.
// Folding: Whh2 = W_hh + W_ih_x@W_reg, bias += W_ih_x@b_reg;
//   gates = Whh2@h_d + W_ih_m@m + W_ih_x@e + b,  e = m*(x - x_h), xc = xh + e.
// Panel ak_s[par][row][k]: k 0..127 h_d | 128..159 e | 160..191 m (pads zero).
// Per-step (par=t&1):
//   P: stg(168 lanes): d(t+1)->d_s[par^1], xm(t+1)->xm_s[par^1], loads t+2
//      all: h*gamma -> panel[par] h-section
//   bar1
//   Q: all: gate MFMAs (accA/accB) + gamma(t+1) MFMA
//      stg: m(t+1)->panel[par^1]; t>0: imp store + loss acc for t-1 (offloaded)
//      wv<2: xh MFMAs -> e -> panel[par] e-section; xc -> xc_s[par]
//   bar2
//   R: e-MFMAs (accB) + combine + pointwise (exp2/rcp, prescaled log2e)
// Race audit identical to r9 (2 buffers, write |bars| read |bars| rewrite all OK).

#define T_LEN 252
#define FEAT  21
#define HID   128
#define BTOT  4096
#define BT    8             // batch rows per block
#define ROWS  16            // MFMA tile rows (BT..15 = zero padding)
#define NB    (BTOT / BT)   // 512 blocks = 2 per CU
#define NTHR  512
#define LOG2E 1.44269504088896f

// ws layout (floats)
#define WS_WHH2   0        // [512][128] folded recurrent weight
#define WS_RDEN   65536    // [256] (252 used)
#define WS_XL     65792    // [512]
#define WS_YNUM   66304    // [512]
#define WS_YDEN   66816    // [512]

typedef __attribute__((ext_vector_type(8))) short s16x8;
typedef __attribute__((ext_vector_type(4))) float f32x4;

#define MFMA16(A, B, C) __builtin_amdgcn_mfma_f32_16x16x32_bf16((A), (B), (C), 0, 0, 0)

__device__ __forceinline__ float exp2_f(float x) { return __builtin_amdgcn_exp2f(x); }
__device__ __forceinline__ float rcp_f(float x)  { return __builtin_amdgcn_rcpf(x); }
__device__ __forceinline__ unsigned short to_bf16(float x) {   // RNE (setup only)
    unsigned int u = __float_as_uint(x);
    return (unsigned short)((u + 0x7FFFu + ((u >> 16) & 1u)) >> 16);
}
__device__ __forceinline__ unsigned short to_bf16f(float x) {  // round-half-up, 2 ops
    return (unsigned short)((__float_as_uint(x) + 0x8000u) >> 16);
}
__device__ __forceinline__ float bf16_to_f(unsigned short u) {
    return __uint_as_float(((unsigned int)u) << 16);
}

// ---- pre-pass 1: rden[t] = 1 / (sum_{b,f} masks[b][t][f] + 1e-5) ----
__global__ __launch_bounds__(1024) void rits_den(
    const float* __restrict__ masks, float* __restrict__ rden)
{
    const int t = blockIdx.x;
    const int tid = threadIdx.x;
    __shared__ float red[1024];
    float acc = 0.0f;
    if (tid < 48 * FEAT) {
        int r0 = tid / FEAT, f = tid - r0 * FEAT;
        for (int r = r0; r < BTOT; r += 48)
            acc += masks[r * (T_LEN * FEAT) + t * FEAT + f];
    }
    red[tid] = acc;
    __syncthreads();
    #pragma unroll
    for (int s = 512; s > 0; s >>= 1) {
        if (tid < s) red[tid] += red[tid + s];
        __syncthreads();
    }
    if (tid == 0) rden[t] = 1.0f / (red[0] + 1e-5f);
}

// ---- pre-pass 2: Whh2 = W_hh + W_ih[:, :FEAT] @ W_reg  (fp32) ----
__global__ __launch_bounds__(256) void rits_fold(
    const float* __restrict__ W_ih, const float* __restrict__ W_hh,
    const float* __restrict__ W_reg, float* __restrict__ whh2)
{
    int idx = blockIdx.x * 256 + threadIdx.x;       // 0..65535
    int j4 = idx >> 7, k = idx & (HID - 1);
    float acc = W_hh[j4 * HID + k];
    #pragma unroll
    for (int f = 0; f < FEAT; ++f)
        acc += W_ih[j4 * (2 * FEAT) + f] * W_reg[f * HID + k];
    whh2[idx] = acc;
}

__global__ __launch_bounds__(NTHR, 4) void rits_main(
    const float* __restrict__ values, const float* __restrict__ masks,
    const float* __restrict__ deltas,
    const float* __restrict__ labels, const float* __restrict__ is_train,
    const float* __restrict__ W_decay, const float* __restrict__ b_decay,
    const float* __restrict__ W_reg, const float* __restrict__ b_reg,
    const float* __restrict__ W_ih, const float* __restrict__ W_hh,
    const float* __restrict__ b_ih, const float* __restrict__ b_hh,
    const float* __restrict__ W_out, const float* __restrict__ b_out,
    const float* __restrict__ whh2, const float* __restrict__ rden,
    float* __restrict__ out_yh,     // [BTOT]
    float* __restrict__ out_imp,    // [BTOT][T][FEAT]
    float* __restrict__ xlpart, float* __restrict__ wsynum, float* __restrict__ wsyden)
{
    const int tid  = threadIdx.x;
    const int blk  = blockIdx.x;
    const int bbase = blk * BT;
    const int l    = tid & 63;
    const int wv   = tid >> 6;          // wave 0..7
    const int cidx = l & 15;
    const int gidx = l >> 4;            // k-group 0..3
    const int jh   = 16 * wv + cidx;    // owned hidden column
    const bool vrow = (gidx < 2);       // D rows 4*gidx+v < BT=8

    __shared__ unsigned short ak_s[2][ROWS][200];
    __shared__ unsigned short d_s[2][ROWS][40];   // bf16 deltas, pads zero
    __shared__ float2 xm_s[2][ROWS][22];          // (x, m) fp32, rows>=BT zero
    __shared__ float xc_s[2][ROWS][22];           // fp32 x_c handoff to stg lanes
    __shared__ float hfin_s[ROWS][HID + 4];
    __shared__ float rden_s[T_LEN];
    __shared__ float red_s[NTHR];

    for (int i = tid; i < 2 * ROWS * 200; i += NTHR) ((unsigned short*)ak_s)[i] = 0;
    for (int i = tid; i < 2 * ROWS * 40;  i += NTHR) ((unsigned short*)d_s)[i] = 0;
    for (int i = tid; i < 2 * ROWS * 22;  i += NTHR) ((float2*)xm_s)[i] = make_float2(0.f, 0.f);
    if (tid < T_LEN) rden_s[tid] = rden[tid];

    // ---------- one-time B-fragments (bf16), gate weights prescaled ----------
    // bfr_g[g][0..3]: Whh2 k 0..127 ; [4]: W_ih_x (e, k 128..159) ; [5]: W_ih_m (m, k 160..191)
    s16x8 bfr_g[4][6];
    float bs_r[4];
    #pragma unroll
    for (int g = 0; g < 4; ++g) {
        const float sg = (g == 2) ? (2.0f * LOG2E) : LOG2E;
        const float* rh2 = whh2 + (g * HID + jh) * HID;
        const float* rih = W_ih + (g * HID + jh) * (2 * FEAT);
        #pragma unroll
        for (int s = 0; s < 4; ++s) {
            s16x8 fr;
            #pragma unroll
            for (int j = 0; j < 8; ++j)
                fr[j] = (short)to_bf16(rh2[32 * s + 8 * gidx + j] * sg);
            bfr_g[g][s] = fr;
        }
        {   // e-part: k 128..159 <-> f = 8*gidx+j
            s16x8 fr;
            #pragma unroll
            for (int j = 0; j < 8; ++j) {
                int f = 8 * gidx + j;
                fr[j] = (short)to_bf16(f < FEAT ? rih[f] * sg : 0.0f);
            }
            bfr_g[g][4] = fr;
        }
        {   // m-part: k 160..191 <-> f = 8*gidx+j
            s16x8 fr;
            #pragma unroll
            for (int j = 0; j < 8; ++j) {
                int fm = 8 * gidx + j;
                fr[j] = (short)to_bf16(fm < FEAT ? rih[FEAT + fm] * sg : 0.0f);
            }
            bfr_g[g][5] = fr;
        }
        float bb = b_ih[g * HID + jh] + b_hh[g * HID + jh];
        #pragma unroll
        for (int f = 0; f < FEAT; ++f) bb += rih[f] * b_reg[f];   // fold b_reg
        bs_r[g] = bb * sg;
    }
    s16x8 bfr_d;
    {
        const float* rw = W_decay + jh * FEAT;
        #pragma unroll
        for (int j = 0; j < 8; ++j) {
            int f = 8 * gidx + j;
            bfr_d[j] = (short)to_bf16(f < FEAT ? rw[f] * LOG2E : 0.0f);
        }
    }
    const float bd_r = b_decay[jh] * LOG2E;
    // x_h weights (waves 0,1 own output col f = 16wv+cidx), NOT prescaled
    const int  fx  = 16 * wv + cidx;
    const bool fxv = (wv < 2) && (fx < FEAT);
    const int  fxc = fxv ? fx : 0;
    s16x8 bfr_r[4];
    #pragma unroll
    for (int s = 0; s < 4; ++s) {
        s16x8 fr;
        #pragma unroll
        for (int j = 0; j < 8; ++j) {
            int k = 32 * s + 8 * gidx + j;
            fr[j] = (short)to_bf16(fxv ? W_reg[fxc * HID + k] : 0.0f);
        }
        bfr_r[s] = fr;
    }
    const float br_r = fxv ? b_reg[fxc] : 0.0f;
    __syncthreads();   // zero-init visible before prologue panel writes

    // ---------- prologue: staging (8 rows x 21 feats = 168 lanes) ----------
    const int st  = tid - 128;
    const bool stg = (st >= 0) && (st < BT * FEAT);
    const int rr = stg ? st / FEAT : 0;
    const int ff = stg ? (st - rr * FEAT) : 0;
    const int rowbase = (bbase + rr) * (T_LEN * FEAT) + ff;
    float nx = 0.f, nm = 0.f, nd = 0.f;
    if (stg) {
        float x0 = values[rowbase], m0 = masks[rowbase];
        xm_s[0][rr][ff] = make_float2(x0, m0);
        ak_s[0][rr][160 + ff] = to_bf16(m0);            // m(0) -> panel[0]
        nx = values[rowbase + FEAT];
        nm = masks[rowbase + FEAT];
        nd = deltas[rowbase + FEAT];
    }
    float c_r[4]   = {0.f, 0.f, 0.f, 0.f};
    float h_r[4]   = {0.f, 0.f, 0.f, 0.f};
    float gam_r[4] = {0.f, 0.f, 0.f, 0.f};   // h=0 at t=0 -> value irrelevant
    float xl_acc = 0.0f;
    __syncthreads();

    #pragma unroll 2
    for (int t = 0; t < T_LEN; ++t) {
        const int par = t & 1;

        // ---- P: flush t+1 stages, issue t+2 loads, h_d -> panel[par] ----
        float lx = 0.f, lm = 0.f, ld = 0.f;
        if (stg) {
            d_s[par ^ 1][rr][ff] = to_bf16f(nd);
            xm_s[par ^ 1][rr][ff] = make_float2(nx, nm);
            int idx = (t + 2 < T_LEN) ? (t + 2) : (T_LEN - 1);
            int o = rowbase + idx * FEAT;
            lx = values[o]; lm = masks[o]; ld = deltas[o];
        }
        #pragma unroll
        for (int v = 0; v < 4; ++v)
            ak_s[par][4 * gidx + v][jh] = to_bf16f(h_r[v] * gam_r[v]);
        __syncthreads();                                // bar1

        // ---- Q ----
        s16x8 aF0 = *(const s16x8*)&ak_s[par][cidx][      8 * gidx];
        s16x8 aF1 = *(const s16x8*)&ak_s[par][cidx][ 32 + 8 * gidx];
        s16x8 aF2 = *(const s16x8*)&ak_s[par][cidx][ 64 + 8 * gidx];
        s16x8 aF3 = *(const s16x8*)&ak_s[par][cidx][ 96 + 8 * gidx];
        s16x8 aM  = *(const s16x8*)&ak_s[par][cidx][160 + 8 * gidx];
        s16x8 ad  = *(const s16x8*)&d_s[par ^ 1][cidx][8 * gidx];
        if (stg) {
            ak_s[par ^ 1][rr][160 + ff] = to_bf16f(nm);   // m(t+1)
            if (t > 0) {   // offloaded imp store + loss for step t-1
                float xcp = xc_s[par ^ 1][rr][ff];
                float ep  = bf16_to_f(ak_s[par ^ 1][rr][128 + ff]);
                out_imp[rowbase + (t - 1) * FEAT] = xcp;
                xl_acc += fabsf(ep) * rden_s[t - 1];
            }
        }

        // gate MFMAs, split chains: accA = b + s0,s1,m ; accB = s2,s3 (+e in R)
        f32x4 accA0 = {bs_r[0], bs_r[0], bs_r[0], bs_r[0]};
        f32x4 accA1 = {bs_r[1], bs_r[1], bs_r[1], bs_r[1]};
        f32x4 accA2 = {bs_r[2], bs_r[2], bs_r[2], bs_r[2]};
        f32x4 accA3 = {bs_r[3], bs_r[3], bs_r[3], bs_r[3]};
        f32x4 accB0 = {0.f, 0.f, 0.f, 0.f};
        f32x4 accB1 = {0.f, 0.f, 0.f, 0.f};
        f32x4 accB2 = {0.f, 0.f, 0.f, 0.f};
        f32x4 accB3 = {0.f, 0.f, 0.f, 0.f};
        accA0 = MFMA16(aF0, bfr_g[0][0], accA0); accA1 = MFMA16(aF0, bfr_g[1][0], accA1);
        accA2 = MFMA16(aF0, bfr_g[2][0], accA2); accA3 = MFMA16(aF0, bfr_g[3][0], accA3);
        accB0 = MFMA16(aF2, bfr_g[0][2], accB0); accB1 = MFMA16(aF2, bfr_g[1][2], accB1);
        accB2 = MFMA16(aF2, bfr_g[2][2], accB2); accB3 = MFMA16(aF2, bfr_g[3][2], accB3);
        accA0 = MFMA16(aF1, bfr_g[0][1], accA0); accA1 = MFMA16(aF1, bfr_g[1][1], accA1);
        accA2 = MFMA16(aF1, bfr_g[2][1], accA2); accA3 = MFMA16(aF1, bfr_g[3][1], accA3);
        accB0 = MFMA16(aF3, bfr_g[0][3], accB0); accB1 = MFMA16(aF3, bfr_g[1][3], accB1);
        accB2 = MFMA16(aF3, bfr_g[2][3], accB2); accB3 = MFMA16(aF3, bfr_g[3][3], accB3);
        accA0 = MFMA16(aM, bfr_g[0][5], accA0);  accA1 = MFMA16(aM, bfr_g[1][5], accA1);
        accA2 = MFMA16(aM, bfr_g[2][5], accA2);  accA3 = MFMA16(aM, bfr_g[3][5], accA3);
        f32x4 gacc = {bd_r, bd_r, bd_r, bd_r};
        gacc = MFMA16(ad, bfr_d, gacc);

        if (wv < 2) {
            // xh split 2+2
            f32x4 x1 = {br_r, br_r, br_r, br_r};
            f32x4 x2 = {0.f, 0.f, 0.f, 0.f};
            x1 = MFMA16(aF0, bfr_r[0], x1);
            x2 = MFMA16(aF2, bfr_r[2], x2);
            x1 = MFMA16(aF1, bfr_r[1], x1);
            x2 = MFMA16(aF3, bfr_r[3], x2);
            if (fxv) {
                #pragma unroll
                for (int v = 0; v < 4; ++v) {
                    float xh = x1[v] + x2[v];
                    float2 xm = xm_s[par][4 * gidx + v][fxc];   // rows>=8: (0,0) -> e=0
                    float e  = xm.y * (xm.x - xh);
                    ak_s[par][4 * gidx + v][128 + fxc] = to_bf16f(e);
                    xc_s[par][4 * gidx + v][fxc] = xh + e;
                }
            }
        }
        if (stg) { nx = lx; nm = lm; nd = ld; }
        __syncthreads();                                // bar2

        // ---- R: e-MFMAs (accB) + combine + pointwise ----
        s16x8 aE = *(const s16x8*)&ak_s[par][cidx][128 + 8 * gidx];
        accB0 = MFMA16(aE, bfr_g[0][4], accB0);
        accB1 = MFMA16(aE, bfr_g[1][4], accB1);
        accB2 = MFMA16(aE, bfr_g[2][4], accB2);
        accB3 = MFMA16(aE, bfr_g[3][4], accB3);
        #pragma unroll
        for (int v = 0; v < 4; ++v) {
            float g0 = accA0[v] + accB0[v];
            float g1 = accA1[v] + accB1[v];
            float g2 = accA2[v] + accB2[v];
            float g3 = accA3[v] + accB3[v];
            float ig = rcp_f(1.0f + exp2_f(-g0));
            float fg = rcp_f(1.0f + exp2_f(-g1));
            float gg = 2.0f * rcp_f(1.0f + exp2_f(-g2)) - 1.0f;
            float og = rcp_f(1.0f + exp2_f(-g3));
            c_r[v] = fg * c_r[v] + ig * gg;
            float th = 2.0f * rcp_f(1.0f + exp2_f(-2.0f * LOG2E * c_r[v])) - 1.0f;
            h_r[v] = vrow ? (og * th) : 0.0f;           // padding rows stay exact 0
            gam_r[v] = exp2_f(-fmaxf(gacc[v], 0.0f));
        }
        // no barrier: P(t+1) writes are barrier-separated per audit
    }

    // ---------- final imp flush for t = T_LEN-1 (par = 1) ----------
    if (stg) {
        float xcp = xc_s[1][rr][ff];
        float ep  = bf16_to_f(ak_s[1][rr][128 + ff]);
        out_imp[rowbase + (T_LEN - 1) * FEAT] = xcp;
        xl_acc += fabsf(ep) * rden_s[T_LEN - 1];
    }

    // ---------- epilogue ----------
    #pragma unroll
    for (int v = 0; v < 4; ++v) hfin_s[4 * gidx + v][jh] = h_r[v];
    red_s[tid] = xl_acc;
    __syncthreads();
    #pragma unroll
    for (int s = NTHR / 2; s > 0; s >>= 1) {
        if (tid < s) red_s[tid] += red_s[tid + s];
        __syncthreads();
    }
    if (tid == 0) xlpart[blk] = red_s[0];

    float yerr = 0.0f, ytr = 0.0f;
    if (tid < BT) {
        float acc = b_out[0];
        for (int k = 0; k < HID; ++k) acc += W_out[k] * hfin_s[tid][k];
        out_yh[bbase + tid] = acc;
        float it = is_train[bbase + tid];
        float dv = acc - labels[bbase + tid];
        yerr = dv * dv * it;
        ytr  = it;
    }
    #pragma unroll
    for (int s = 4; s > 0; s >>= 1) {
        yerr += __shfl_down(yerr, s);
        ytr  += __shfl_down(ytr, s);
    }
    if (tid == 0) { wsynum[blk] = yerr; wsyden[blk] = ytr; }
}

__global__ __launch_bounds__(256) void rits_final(
    const float* __restrict__ xlpart,
    const float* __restrict__ wsynum, const float* __restrict__ wsyden,
    float* __restrict__ d_out)
{
    __shared__ float sx[256], sy[256], sz[256];
    int tid = threadIdx.x;
    sx[tid] = xlpart[tid] + xlpart[tid + 256];
    sy[tid] = wsynum[tid] + wsynum[tid + 256];
    sz[tid] = wsyden[tid] + wsyden[tid + 256];
    __syncthreads();
    for (int s = 128; s > 0; s >>= 1) {
        if (tid < s) { sx[tid] += sx[tid + s]; sy[tid] += sy[tid + s]; sz[tid] += sz[tid + s]; }
        __syncthreads();
    }
    if (tid == 0) d_out[0] = sx[0] + sy[0] / (sz[0] + 1e-5f);
}

extern "C" void kernel_launch(void* const* d_in, const int* in_sizes, int n_in,
                              void* d_out, int out_size, void* d_ws, size_t ws_size,
                              hipStream_t stream)
{
    const float* values    = (const float*)d_in[0];
    const float* masks     = (const float*)d_in[1];
    const float* deltas    = (const float*)d_in[2];
    // d_in[3] evals, d_in[4] eval_masks : unused
    const float* labels    = (const float*)d_in[5];
    const float* is_train  = (const float*)d_in[6];
    const float* W_decay   = (const float*)d_in[7];
    const float* b_decay   = (const float*)d_in[8];
    const float* W_reg     = (const float*)d_in[9];
    const float* b_reg     = (const float*)d_in[10];
    const float* W_ih      = (const float*)d_in[11];
    const float* W_hh      = (const float*)d_in[12];
    const float* b_ih      = (const float*)d_in[13];
    const float* b_hh      = (const float*)d_in[14];
    const float* W_out     = (const float*)d_in[15];
    const float* b_out     = (const float*)d_in[16];

    float* ws     = (float*)d_ws;
    float* whh2   = ws + WS_WHH2;
    float* rden   = ws + WS_RDEN;
    float* xlpart = ws + WS_XL;
    float* wsynum = ws + WS_YNUM;
    float* wsyden = ws + WS_YDEN;

    float* out     = (float*)d_out;
    float* out_yh  = out + 1;
    float* out_imp = out + 1 + BTOT;

    rits_den<<<dim3(T_LEN), dim3(1024), 0, stream>>>(masks, rden);
    rits_fold<<<dim3(256), dim3(256), 0, stream>>>(W_ih, W_hh, W_reg, whh2);

    rits_main<<<dim3(NB), dim3(NTHR), 0, stream>>>(
        values, masks, deltas, labels, is_train,
        W_decay, b_decay, W_reg, b_reg, W_ih, W_hh, b_ih, b_hh, W_out, b_out,
        whh2, rden, out_yh, out_imp, xlpart, wsynum, wsyden);

    rits_final<<<dim3(1), dim3(256), 0, stream>>>(xlpart, wsynum, wsyden, out);
}

// Round 12
// 734.582 us; speedup vs baseline: 4.0302x; 4.0302x over previous
//
#include <hip/hip_runtime.h>
#include <math.h>

// RITS recurrent model, MFMA bf16, r9 structure, 2 blocks/CU — FIXED VGPR cap.
// r11 failed because __launch_bounds__ 2nd arg is CUDA-style min BLOCKS per CU:
// (512,4) -> 32 waves/CU -> VGPR=64 -> weight spills -> 9.8 GB scratch traffic.
// Here: __launch_bounds__(512, 2) -> 16 waves/CU cap -> VGPR=128 (no spill),
// grid=512, LDS 35KB -> two independent blocks per CU, disjoint barrier groups.
// 512 blocks x 512 threads (8 waves); each block owns 8 batch rows (MFMA tiles
// padded to 16 rows; padding rows exact zeros: h_r masked, xm_s zero-init).
// Wave w owns jh cols [16w,16w+16). MFMA 16x16x32 lane layout (m89-verified):
//   cidx=l&15 (A row / D col), gidx=l>>4; D: row=4*gidx+v, col=cidx.
// Folding: Whh2 = W_hh + W_ih_x@W_reg, bias += W_ih_x@b_reg;
//   gates = Whh2@h_d + W_ih_m@m + W_ih_x@e + b,  e = m*(x - x_h), xc = xh + e.
// Panel ak_s[par][row][k]: k 0..127 h_d | 128..159 e | 160..191 m (pads zero).
// Per-step (par=t&1):
//   P: stg(168 lanes): d(t+1)->d_s[par^1], xm(t+1)->xm_s[par^1], loads t+2
//      all: h*gamma -> panel[par] h-section
//   bar1
//   Q: all: gate MFMAs (accA/accB) + gamma(t+1) MFMA
//      stg: m(t+1)->panel[par^1]; t>0: imp store + loss acc for t-1 (offloaded)
//      wv<2: xh MFMAs -> e -> panel[par] e-section; xc -> xc_s[par]
//   bar2
//   R: e-MFMAs (accB) + combine + pointwise (exp2/rcp, prescaled log2e)
// Race audit identical to r9 (2 buffers, write |bars| read |bars| rewrite OK).

#define T_LEN 252
#define FEAT  21
#define HID   128
#define BTOT  4096
#define BT    8             // batch rows per block
#define ROWS  16            // MFMA tile rows (BT..15 = zero padding)
#define NB    (BTOT / BT)   // 512 blocks = 2 per CU
#define NTHR  512
#define LOG2E 1.44269504088896f

// ws layout (floats)
#define WS_WHH2   0        // [512][128] folded recurrent weight
#define WS_RDEN   65536    // [256] (252 used)
#define WS_XL     65792    // [512]
#define WS_YNUM   66304    // [512]
#define WS_YDEN   66816    // [512]

typedef __attribute__((ext_vector_type(8))) short s16x8;
typedef __attribute__((ext_vector_type(4))) float f32x4;

#define MFMA16(A, B, C) __builtin_amdgcn_mfma_f32_16x16x32_bf16((A), (B), (C), 0, 0, 0)

__device__ __forceinline__ float exp2_f(float x) { return __builtin_amdgcn_exp2f(x); }
__device__ __forceinline__ float rcp_f(float x)  { return __builtin_amdgcn_rcpf(x); }
__device__ __forceinline__ unsigned short to_bf16(float x) {   // RNE (setup only)
    unsigned int u = __float_as_uint(x);
    return (unsigned short)((u + 0x7FFFu + ((u >> 16) & 1u)) >> 16);
}
__device__ __forceinline__ unsigned short to_bf16f(float x) {  // round-half-up, 2 ops
    return (unsigned short)((__float_as_uint(x) + 0x8000u) >> 16);
}
__device__ __forceinline__ float bf16_to_f(unsigned short u) {
    return __uint_as_float(((unsigned int)u) << 16);
}

// ---- pre-pass 1: rden[t] = 1 / (sum_{b,f} masks[b][t][f] + 1e-5) ----
__global__ __launch_bounds__(1024) void rits_den(
    const float* __restrict__ masks, float* __restrict__ rden)
{
    const int t = blockIdx.x;
    const int tid = threadIdx.x;
    __shared__ float red[1024];
    float acc = 0.0f;
    if (tid < 48 * FEAT) {
        int r0 = tid / FEAT, f = tid - r0 * FEAT;
        for (int r = r0; r < BTOT; r += 48)
            acc += masks[r * (T_LEN * FEAT) + t * FEAT + f];
    }
    red[tid] = acc;
    __syncthreads();
    #pragma unroll
    for (int s = 512; s > 0; s >>= 1) {
        if (tid < s) red[tid] += red[tid + s];
        __syncthreads();
    }
    if (tid == 0) rden[t] = 1.0f / (red[0] + 1e-5f);
}

// ---- pre-pass 2: Whh2 = W_hh + W_ih[:, :FEAT] @ W_reg  (fp32) ----
__global__ __launch_bounds__(256) void rits_fold(
    const float* __restrict__ W_ih, const float* __restrict__ W_hh,
    const float* __restrict__ W_reg, float* __restrict__ whh2)
{
    int idx = blockIdx.x * 256 + threadIdx.x;       // 0..65535
    int j4 = idx >> 7, k = idx & (HID - 1);
    float acc = W_hh[j4 * HID + k];
    #pragma unroll
    for (int f = 0; f < FEAT; ++f)
        acc += W_ih[j4 * (2 * FEAT) + f] * W_reg[f * HID + k];
    whh2[idx] = acc;
}

__global__ __launch_bounds__(NTHR, 2) void rits_main(
    const float* __restrict__ values, const float* __restrict__ masks,
    const float* __restrict__ deltas,
    const float* __restrict__ labels, const float* __restrict__ is_train,
    const float* __restrict__ W_decay, const float* __restrict__ b_decay,
    const float* __restrict__ W_reg, const float* __restrict__ b_reg,
    const float* __restrict__ W_ih, const float* __restrict__ W_hh,
    const float* __restrict__ b_ih, const float* __restrict__ b_hh,
    const float* __restrict__ W_out, const float* __restrict__ b_out,
    const float* __restrict__ whh2, const float* __restrict__ rden,
    float* __restrict__ out_yh,     // [BTOT]
    float* __restrict__ out_imp,    // [BTOT][T][FEAT]
    float* __restrict__ xlpart, float* __restrict__ wsynum, float* __restrict__ wsyden)
{
    const int tid  = threadIdx.x;
    const int blk  = blockIdx.x;
    const int bbase = blk * BT;
    const int l    = tid & 63;
    const int wv   = tid >> 6;          // wave 0..7
    const int cidx = l & 15;
    const int gidx = l >> 4;            // k-group 0..3
    const int jh   = 16 * wv + cidx;    // owned hidden column
    const bool vrow = (gidx < 2);       // D rows 4*gidx+v < BT=8

    __shared__ unsigned short ak_s[2][ROWS][200];
    __shared__ unsigned short d_s[2][ROWS][40];   // bf16 deltas, pads zero
    __shared__ float2 xm_s[2][ROWS][22];          // (x, m) fp32, rows>=BT zero
    __shared__ float xc_s[2][ROWS][22];           // fp32 x_c handoff to stg lanes
    __shared__ float hfin_s[ROWS][HID + 4];
    __shared__ float rden_s[T_LEN];
    __shared__ float red_s[NTHR];

    for (int i = tid; i < 2 * ROWS * 200; i += NTHR) ((unsigned short*)ak_s)[i] = 0;
    for (int i = tid; i < 2 * ROWS * 40;  i += NTHR) ((unsigned short*)d_s)[i] = 0;
    for (int i = tid; i < 2 * ROWS * 22;  i += NTHR) ((float2*)xm_s)[i] = make_float2(0.f, 0.f);
    if (tid < T_LEN) rden_s[tid] = rden[tid];

    // ---------- one-time B-fragments (bf16), gate weights prescaled ----------
    // bfr_g[g][0..3]: Whh2 k 0..127 ; [4]: W_ih_x (e, k 128..159) ; [5]: W_ih_m (m, k 160..191)
    s16x8 bfr_g[4][6];
    float bs_r[4];
    #pragma unroll
    for (int g = 0; g < 4; ++g) {
        const float sg = (g == 2) ? (2.0f * LOG2E) : LOG2E;
        const float* rh2 = whh2 + (g * HID + jh) * HID;
        const float* rih = W_ih + (g * HID + jh) * (2 * FEAT);
        #pragma unroll
        for (int s = 0; s < 4; ++s) {
            s16x8 fr;
            #pragma unroll
            for (int j = 0; j < 8; ++j)
                fr[j] = (short)to_bf16(rh2[32 * s + 8 * gidx + j] * sg);
            bfr_g[g][s] = fr;
        }
        {   // e-part: k 128..159 <-> f = 8*gidx+j
            s16x8 fr;
            #pragma unroll
            for (int j = 0; j < 8; ++j) {
                int f = 8 * gidx + j;
                fr[j] = (short)to_bf16(f < FEAT ? rih[f] * sg : 0.0f);
            }
            bfr_g[g][4] = fr;
        }
        {   // m-part: k 160..191 <-> f = 8*gidx+j
            s16x8 fr;
            #pragma unroll
            for (int j = 0; j < 8; ++j) {
                int fm = 8 * gidx + j;
                fr[j] = (short)to_bf16(fm < FEAT ? rih[FEAT + fm] * sg : 0.0f);
            }
            bfr_g[g][5] = fr;
        }
        float bb = b_ih[g * HID + jh] + b_hh[g * HID + jh];
        #pragma unroll
        for (int f = 0; f < FEAT; ++f) bb += rih[f] * b_reg[f];   // fold b_reg
        bs_r[g] = bb * sg;
    }
    s16x8 bfr_d;
    {
        const float* rw = W_decay + jh * FEAT;
        #pragma unroll
        for (int j = 0; j < 8; ++j) {
            int f = 8 * gidx + j;
            bfr_d[j] = (short)to_bf16(f < FEAT ? rw[f] * LOG2E : 0.0f);
        }
    }
    const float bd_r = b_decay[jh] * LOG2E;
    // x_h weights (waves 0,1 own output col f = 16wv+cidx), NOT prescaled
    const int  fx  = 16 * wv + cidx;
    const bool fxv = (wv < 2) && (fx < FEAT);
    const int  fxc = fxv ? fx : 0;
    s16x8 bfr_r[4];
    #pragma unroll
    for (int s = 0; s < 4; ++s) {
        s16x8 fr;
        #pragma unroll
        for (int j = 0; j < 8; ++j) {
            int k = 32 * s + 8 * gidx + j;
            fr[j] = (short)to_bf16(fxv ? W_reg[fxc * HID + k] : 0.0f);
        }
        bfr_r[s] = fr;
    }
    const float br_r = fxv ? b_reg[fxc] : 0.0f;
    __syncthreads();   // zero-init visible before prologue panel writes

    // ---------- prologue: staging (8 rows x 21 feats = 168 lanes) ----------
    const int st  = tid - 128;
    const bool stg = (st >= 0) && (st < BT * FEAT);
    const int rr = stg ? st / FEAT : 0;
    const int ff = stg ? (st - rr * FEAT) : 0;
    const int rowbase = (bbase + rr) * (T_LEN * FEAT) + ff;
    float nx = 0.f, nm = 0.f, nd = 0.f;
    if (stg) {
        float x0 = values[rowbase], m0 = masks[rowbase];
        xm_s[0][rr][ff] = make_float2(x0, m0);
        ak_s[0][rr][160 + ff] = to_bf16(m0);            // m(0) -> panel[0]
        nx = values[rowbase + FEAT];
        nm = masks[rowbase + FEAT];
        nd = deltas[rowbase + FEAT];
    }
    float c_r[4]   = {0.f, 0.f, 0.f, 0.f};
    float h_r[4]   = {0.f, 0.f, 0.f, 0.f};
    float gam_r[4] = {0.f, 0.f, 0.f, 0.f};   // h=0 at t=0 -> value irrelevant
    float xl_acc = 0.0f;
    __syncthreads();

    #pragma unroll 2
    for (int t = 0; t < T_LEN; ++t) {
        const int par = t & 1;

        // ---- P: flush t+1 stages, issue t+2 loads, h_d -> panel[par] ----
        float lx = 0.f, lm = 0.f, ld = 0.f;
        if (stg) {
            d_s[par ^ 1][rr][ff] = to_bf16f(nd);
            xm_s[par ^ 1][rr][ff] = make_float2(nx, nm);
            int idx = (t + 2 < T_LEN) ? (t + 2) : (T_LEN - 1);
            int o = rowbase + idx * FEAT;
            lx = values[o]; lm = masks[o]; ld = deltas[o];
        }
        #pragma unroll
        for (int v = 0; v < 4; ++v)
            ak_s[par][4 * gidx + v][jh] = to_bf16f(h_r[v] * gam_r[v]);
        __syncthreads();                                // bar1

        // ---- Q ----
        s16x8 aF0 = *(const s16x8*)&ak_s[par][cidx][      8 * gidx];
        s16x8 aF1 = *(const s16x8*)&ak_s[par][cidx][ 32 + 8 * gidx];
        s16x8 aF2 = *(const s16x8*)&ak_s[par][cidx][ 64 + 8 * gidx];
        s16x8 aF3 = *(const s16x8*)&ak_s[par][cidx][ 96 + 8 * gidx];
        s16x8 aM  = *(const s16x8*)&ak_s[par][cidx][160 + 8 * gidx];
        s16x8 ad  = *(const s16x8*)&d_s[par ^ 1][cidx][8 * gidx];
        if (stg) {
            ak_s[par ^ 1][rr][160 + ff] = to_bf16f(nm);   // m(t+1)
            if (t > 0) {   // offloaded imp store + loss for step t-1
                float xcp = xc_s[par ^ 1][rr][ff];
                float ep  = bf16_to_f(ak_s[par ^ 1][rr][128 + ff]);
                out_imp[rowbase + (t - 1) * FEAT] = xcp;
                xl_acc += fabsf(ep) * rden_s[t - 1];
            }
        }

        // gate MFMAs, split chains: accA = b + s0,s1,m ; accB = s2,s3 (+e in R)
        f32x4 accA0 = {bs_r[0], bs_r[0], bs_r[0], bs_r[0]};
        f32x4 accA1 = {bs_r[1], bs_r[1], bs_r[1], bs_r[1]};
        f32x4 accA2 = {bs_r[2], bs_r[2], bs_r[2], bs_r[2]};
        f32x4 accA3 = {bs_r[3], bs_r[3], bs_r[3], bs_r[3]};
        f32x4 accB0 = {0.f, 0.f, 0.f, 0.f};
        f32x4 accB1 = {0.f, 0.f, 0.f, 0.f};
        f32x4 accB2 = {0.f, 0.f, 0.f, 0.f};
        f32x4 accB3 = {0.f, 0.f, 0.f, 0.f};
        accA0 = MFMA16(aF0, bfr_g[0][0], accA0); accA1 = MFMA16(aF0, bfr_g[1][0], accA1);
        accA2 = MFMA16(aF0, bfr_g[2][0], accA2); accA3 = MFMA16(aF0, bfr_g[3][0], accA3);
        accB0 = MFMA16(aF2, bfr_g[0][2], accB0); accB1 = MFMA16(aF2, bfr_g[1][2], accB1);
        accB2 = MFMA16(aF2, bfr_g[2][2], accB2); accB3 = MFMA16(aF2, bfr_g[3][2], accB3);
        accA0 = MFMA16(aF1, bfr_g[0][1], accA0); accA1 = MFMA16(aF1, bfr_g[1][1], accA1);
        accA2 = MFMA16(aF1, bfr_g[2][1], accA2); accA3 = MFMA16(aF1, bfr_g[3][1], accA3);
        accB0 = MFMA16(aF3, bfr_g[0][3], accB0); accB1 = MFMA16(aF3, bfr_g[1][3], accB1);
        accB2 = MFMA16(aF3, bfr_g[2][3], accB2); accB3 = MFMA16(aF3, bfr_g[3][3], accB3);
        accA0 = MFMA16(aM, bfr_g[0][5], accA0);  accA1 = MFMA16(aM, bfr_g[1][5], accA1);
        accA2 = MFMA16(aM, bfr_g[2][5], accA2);  accA3 = MFMA16(aM, bfr_g[3][5], accA3);
        f32x4 gacc = {bd_r, bd_r, bd_r, bd_r};
        gacc = MFMA16(ad, bfr_d, gacc);

        if (wv < 2) {
            // xh split 2+2
            f32x4 x1 = {br_r, br_r, br_r, br_r};
            f32x4 x2 = {0.f, 0.f, 0.f, 0.f};
            x1 = MFMA16(aF0, bfr_r[0], x1);
            x2 = MFMA16(aF2, bfr_r[2], x2);
            x1 = MFMA16(aF1, bfr_r[1], x1);
            x2 = MFMA16(aF3, bfr_r[3], x2);
            if (fxv) {
                #pragma unroll
                for (int v = 0; v < 4; ++v) {
                    float xh = x1[v] + x2[v];
                    float2 xm = xm_s[par][4 * gidx + v][fxc];   // rows>=8: (0,0) -> e=0
                    float e  = xm.y * (xm.x - xh);
                    ak_s[par][4 * gidx + v][128 + fxc] = to_bf16f(e);
                    xc_s[par][4 * gidx + v][fxc] = xh + e;
                }
            }
        }
        if (stg) { nx = lx; nm = lm; nd = ld; }
        __syncthreads();                                // bar2

        // ---- R: e-MFMAs (accB) + combine + pointwise ----
        s16x8 aE = *(const s16x8*)&ak_s[par][cidx][128 + 8 * gidx];
        accB0 = MFMA16(aE, bfr_g[0][4], accB0);
        accB1 = MFMA16(aE, bfr_g[1][4], accB1);
        accB2 = MFMA16(aE, bfr_g[2][4], accB2);
        accB3 = MFMA16(aE, bfr_g[3][4], accB3);
        #pragma unroll
        for (int v = 0; v < 4; ++v) {
            float g0 = accA0[v] + accB0[v];
            float g1 = accA1[v] + accB1[v];
            float g2 = accA2[v] + accB2[v];
            float g3 = accA3[v] + accB3[v];
            float ig = rcp_f(1.0f + exp2_f(-g0));
            float fg = rcp_f(1.0f + exp2_f(-g1));
            float gg = 2.0f * rcp_f(1.0f + exp2_f(-g2)) - 1.0f;
            float og = rcp_f(1.0f + exp2_f(-g3));
            c_r[v] = fg * c_r[v] + ig * gg;
            float th = 2.0f * rcp_f(1.0f + exp2_f(-2.0f * LOG2E * c_r[v])) - 1.0f;
            h_r[v] = vrow ? (og * th) : 0.0f;           // padding rows stay exact 0
            gam_r[v] = exp2_f(-fmaxf(gacc[v], 0.0f));
        }
        // no barrier: P(t+1) writes are barrier-separated per audit
    }

    // ---------- final imp flush for t = T_LEN-1 (par = 1) ----------
    if (stg) {
        float xcp = xc_s[1][rr][ff];
        float ep  = bf16_to_f(ak_s[1][rr][128 + ff]);
        out_imp[rowbase + (T_LEN - 1) * FEAT] = xcp;
        xl_acc += fabsf(ep) * rden_s[T_LEN - 1];
    }

    // ---------- epilogue ----------
    #pragma unroll
    for (int v = 0; v < 4; ++v) hfin_s[4 * gidx + v][jh] = h_r[v];
    red_s[tid] = xl_acc;
    __syncthreads();
    #pragma unroll
    for (int s = NTHR / 2; s > 0; s >>= 1) {
        if (tid < s) red_s[tid] += red_s[tid + s];
        __syncthreads();
    }
    if (tid == 0) xlpart[blk] = red_s[0];

    float yerr = 0.0f, ytr = 0.0f;
    if (tid < BT) {
        float acc = b_out[0];
        for (int k = 0; k < HID; ++k) acc += W_out[k] * hfin_s[tid][k];
        out_yh[bbase + tid] = acc;
        float it = is_train[bbase + tid];
        float dv = acc - labels[bbase + tid];
        yerr = dv * dv * it;
        ytr  = it;
    }
    #pragma unroll
    for (int s = 4; s > 0; s >>= 1) {
        yerr += __shfl_down(yerr, s);
        ytr  += __shfl_down(ytr, s);
    }
    if (tid == 0) { wsynum[blk] = yerr; wsyden[blk] = ytr; }
}

__global__ __launch_bounds__(256) void rits_final(
    const float* __restrict__ xlpart,
    const float* __restrict__ wsynum, const float* __restrict__ wsyden,
    float* __restrict__ d_out)
{
    __shared__ float sx[256], sy[256], sz[256];
    int tid = threadIdx.x;
    sx[tid] = xlpart[tid] + xlpart[tid + 256];
    sy[tid] = wsynum[tid] + wsynum[tid + 256];
    sz[tid] = wsyden[tid] + wsyden[tid + 256];
    __syncthreads();
    for (int s = 128; s > 0; s >>= 1) {
        if (tid < s) { sx[tid] += sx[tid + s]; sy[tid] += sy[tid + s]; sz[tid] += sz[tid + s]; }
        __syncthreads();
    }
    if (tid == 0) d_out[0] = sx[0] + sy[0] / (sz[0] + 1e-5f);
}

extern "C" void kernel_launch(void* const* d_in, const int* in_sizes, int n_in,
                              void* d_out, int out_size, void* d_ws, size_t ws_size,
                              hipStream_t stream)
{
    const float* values    = (const float*)d_in[0];
    const float* masks     = (const float*)d_in[1];
    const float* deltas    = (const float*)d_in[2];
    // d_in[3] evals, d_in[4] eval_masks : unused
    const float* labels    = (const float*)d_in[5];
    const float* is_train  = (const float*)d_in[6];
    const float* W_decay   = (const float*)d_in[7];
    const float* b_decay   = (const float*)d_in[8];
    const float* W_reg     = (const float*)d_in[9];
    const float* b_reg     = (const float*)d_in[10];
    const float* W_ih      = (const float*)d_in[11];
    const float* W_hh      = (const float*)d_in[12];
    const float* b_ih      = (const float*)d_in[13];
    const float* b_hh      = (const float*)d_in[14];
    const float* W_out     = (const float*)d_in[15];
    const float* b_out     = (const float*)d_in[16];

    float* ws     = (float*)d_ws;
    float* whh2   = ws + WS_WHH2;
    float* rden   = ws + WS_RDEN;
    float* xlpart = ws + WS_XL;
    float* wsynum = ws + WS_YNUM;
    float* wsyden = ws + WS_YDEN;

    float* out     = (float*)d_out;
    float* out_yh  = out + 1;
    float* out_imp = out + 1 + BTOT;

    rits_den<<<dim3(T_LEN), dim3(1024), 0, stream>>>(masks, rden);
    rits_fold<<<dim3(256), dim3(256), 0, stream>>>(W_ih, W_hh, W_reg, whh2);

    rits_main<<<dim3(NB), dim3(NTHR), 0, stream>>>(
        values, masks, deltas, labels, is_train,
        W_decay, b_decay, W_reg, b_reg, W_ih, W_hh, b_ih, b_hh, W_out, b_out,
        whh2, rden, out_yh, out_imp, xlpart, wsynum, wsyden);

    rits_final<<<dim3(1), dim3(256), 0, stream>>>(xlpart, wsynum, wsyden, out);
}

// Round 13
// 400.035 us; speedup vs baseline: 7.4006x; 1.8363x over previous
//
#include <hip/hip_runtime.h>
#include <math.h>

// RITS recurrent model, MFMA bf16, 2-barrier step — CHAMPION (r9, 401 µs).
// Reverted after r10 (sched bundle, neutral-negative), r11 (launch_bounds
// blocks-semantics spill, 7.4x), r12 (BT=8 padding doubles issued work, 1.8x).
// 256 blocks x 512 threads (8 waves), block owns 16 batch rows.
// Wave w owns jh cols [16w,16w+16). MFMA 16x16x32 lane layout (m89-verified):
//   cidx=l&15 (A row / D col), gidx=l>>4; D: row=4*gidx+v, col=cidx.
// Folding: Whh2 = W_hh + W_ih_x@W_reg, bias += W_ih_x@b_reg;
//   gates = Whh2@h_d + W_ih_m@m + W_ih_x@e + b,  e = m*(x - x_h), xc = xh + e.
// Panel ak_s[par][row][k]: k 0..127 h_d | 128..159 e | 160..191 m (pads zero).
// Per-step (par=t&1):
//   P: stg: d(t+1)->d_s[par^1], xm(t+1)->xm_s[par^1], issue loads t+2
//      all: h*gamma -> panel[par] h-section
//   bar1
//   Q: all: gate MFMAs (accA/accB) + gamma(t+1) MFMA
//      stg: m(t+1)->panel[par^1]; t>0: imp store + loss acc for t-1 (offloaded)
//      wv<2: xh MFMAs -> e -> panel[par] e-section; xc -> xc_s[par]
//   bar2
//   R: e-MFMAs (accB) + combine + pointwise (exp2/rcp, prescaled log2e)
// Race audit (write | bars | read | bars | rewrite), 2 buffers each:
//   h panel[par]: W P(t) |b1| R Q(t) |b2,b1| W P(t+2)            OK
//   e panel[par]: W Q(t) |b2,b1| R R(t)+Qstg(t+1) |b2,b1| W Q(t+2) OK
//   m panel[par^1]: W Q(t) |b2,b1| R Q(t+1) |b2,b1| W Q(t+2)     OK
//   d_s[par^1]: W P(t) |b1| R Q(t) |b2,b1| W P(t+2)              OK
//   xm_s[par^1]: W P(t) |b1,b2,b1| R Q(t+1) |b2| W P(t+2)        OK
//   xc_s[par]: W Q(t) |b2,b1| R Qstg(t+1) |b2,b1| W Q(t+2)       OK

#define T_LEN 252
#define FEAT  21
#define HID   128
#define BTOT  4096
#define BT    16
#define NB    (BTOT / BT)   // 256
#define NTHR  512
#define LOG2E 1.44269504088896f

// ws layout (floats)
#define WS_WHH2   0        // [512][128] folded recurrent weight
#define WS_RDEN   65536    // [256] (252 used)
#define WS_XL     65792    // [256]
#define WS_YNUM   66048    // [256]
#define WS_YDEN   66304    // [256]

typedef __attribute__((ext_vector_type(8))) short s16x8;
typedef __attribute__((ext_vector_type(4))) float f32x4;

#define MFMA16(A, B, C) __builtin_amdgcn_mfma_f32_16x16x32_bf16((A), (B), (C), 0, 0, 0)

__device__ __forceinline__ float exp2_f(float x) { return __builtin_amdgcn_exp2f(x); }
__device__ __forceinline__ float rcp_f(float x)  { return __builtin_amdgcn_rcpf(x); }
__device__ __forceinline__ unsigned short to_bf16(float x) {   // RNE (setup only)
    unsigned int u = __float_as_uint(x);
    return (unsigned short)((u + 0x7FFFu + ((u >> 16) & 1u)) >> 16);
}
__device__ __forceinline__ unsigned short to_bf16f(float x) {  // round-half-up, 2 ops
    return (unsigned short)((__float_as_uint(x) + 0x8000u) >> 16);
}
__device__ __forceinline__ float bf16_to_f(unsigned short u) {
    return __uint_as_float(((unsigned int)u) << 16);
}

// ---- pre-pass 1: rden[t] = 1 / (sum_{b,f} masks[b][t][f] + 1e-5) ----
__global__ __launch_bounds__(1024) void rits_den(
    const float* __restrict__ masks, float* __restrict__ rden)
{
    const int t = blockIdx.x;
    const int tid = threadIdx.x;
    __shared__ float red[1024];
    float acc = 0.0f;
    if (tid < 48 * FEAT) {
        int r0 = tid / FEAT, f = tid - r0 * FEAT;
        for (int r = r0; r < BTOT; r += 48)
            acc += masks[r * (T_LEN * FEAT) + t * FEAT + f];
    }
    red[tid] = acc;
    __syncthreads();
    #pragma unroll
    for (int s = 512; s > 0; s >>= 1) {
        if (tid < s) red[tid] += red[tid + s];
        __syncthreads();
    }
    if (tid == 0) rden[t] = 1.0f / (red[0] + 1e-5f);
}

// ---- pre-pass 2: Whh2 = W_hh + W_ih[:, :FEAT] @ W_reg  (fp32) ----
__global__ __launch_bounds__(256) void rits_fold(
    const float* __restrict__ W_ih, const float* __restrict__ W_hh,
    const float* __restrict__ W_reg, float* __restrict__ whh2)
{
    int idx = blockIdx.x * 256 + threadIdx.x;       // 0..65535
    int j4 = idx >> 7, k = idx & (HID - 1);
    float acc = W_hh[j4 * HID + k];
    #pragma unroll
    for (int f = 0; f < FEAT; ++f)
        acc += W_ih[j4 * (2 * FEAT) + f] * W_reg[f * HID + k];
    whh2[idx] = acc;
}

__global__ __launch_bounds__(NTHR, 2) void rits_main(
    const float* __restrict__ values, const float* __restrict__ masks,
    const float* __restrict__ deltas,
    const float* __restrict__ labels, const float* __restrict__ is_train,
    const float* __restrict__ W_decay, const float* __restrict__ b_decay,
    const float* __restrict__ W_reg, const float* __restrict__ b_reg,
    const float* __restrict__ W_ih, const float* __restrict__ W_hh,
    const float* __restrict__ b_ih, const float* __restrict__ b_hh,
    const float* __restrict__ W_out, const float* __restrict__ b_out,
    const float* __restrict__ whh2, const float* __restrict__ rden,
    float* __restrict__ out_yh,     // [BTOT]
    float* __restrict__ out_imp,    // [BTOT][T][FEAT]
    float* __restrict__ xlpart, float* __restrict__ wsynum, float* __restrict__ wsyden)
{
    const int tid  = threadIdx.x;
    const int blk  = blockIdx.x;
    const int bbase = blk * BT;
    const int l    = tid & 63;
    const int wv   = tid >> 6;          // wave 0..7
    const int cidx = l & 15;
    const int gidx = l >> 4;            // k-group 0..3
    const int jh   = 16 * wv + cidx;    // owned hidden column

    __shared__ unsigned short ak_s[2][BT][200];
    __shared__ unsigned short d_s[2][BT][40];     // bf16 deltas, cols 21..39 zero
    __shared__ float2 xm_s[2][BT][22];            // (x, m) fp32
    __shared__ float xc_s[2][BT][22];             // fp32 x_c handoff to stg lanes
    __shared__ float hfin_s[BT][HID + 4];
    __shared__ float rden_s[T_LEN];
    __shared__ float red_s[NTHR];

    for (int i = tid; i < 2 * BT * 200; i += NTHR) ((unsigned short*)ak_s)[i] = 0;
    for (int i = tid; i < 2 * BT * 40;  i += NTHR) ((unsigned short*)d_s)[i] = 0;
    if (tid < T_LEN) rden_s[tid] = rden[tid];

    // ---------- one-time B-fragments (bf16), gate weights prescaled ----------
    // bfr_g[g][0..3]: Whh2 k 0..127 ; [4]: W_ih_x (e, k 128..159) ; [5]: W_ih_m (m, k 160..191)
    s16x8 bfr_g[4][6];
    float bs_r[4];
    #pragma unroll
    for (int g = 0; g < 4; ++g) {
        const float sg = (g == 2) ? (2.0f * LOG2E) : LOG2E;
        const float* rh2 = whh2 + (g * HID + jh) * HID;
        const float* rih = W_ih + (g * HID + jh) * (2 * FEAT);
        #pragma unroll
        for (int s = 0; s < 4; ++s) {
            s16x8 fr;
            #pragma unroll
            for (int j = 0; j < 8; ++j)
                fr[j] = (short)to_bf16(rh2[32 * s + 8 * gidx + j] * sg);
            bfr_g[g][s] = fr;
        }
        {   // e-part: k 128..159 <-> f = 8*gidx+j
            s16x8 fr;
            #pragma unroll
            for (int j = 0; j < 8; ++j) {
                int f = 8 * gidx + j;
                fr[j] = (short)to_bf16(f < FEAT ? rih[f] * sg : 0.0f);
            }
            bfr_g[g][4] = fr;
        }
        {   // m-part: k 160..191 <-> f = 8*gidx+j
            s16x8 fr;
            #pragma unroll
            for (int j = 0; j < 8; ++j) {
                int fm = 8 * gidx + j;
                fr[j] = (short)to_bf16(fm < FEAT ? rih[FEAT + fm] * sg : 0.0f);
            }
            bfr_g[g][5] = fr;
        }
        float bb = b_ih[g * HID + jh] + b_hh[g * HID + jh];
        #pragma unroll
        for (int f = 0; f < FEAT; ++f) bb += rih[f] * b_reg[f];   // fold b_reg
        bs_r[g] = bb * sg;
    }
    s16x8 bfr_d;
    {
        const float* rw = W_decay + jh * FEAT;
        #pragma unroll
        for (int j = 0; j < 8; ++j) {
            int f = 8 * gidx + j;
            bfr_d[j] = (short)to_bf16(f < FEAT ? rw[f] * LOG2E : 0.0f);
        }
    }
    const float bd_r = b_decay[jh] * LOG2E;
    // x_h weights (waves 0,1 own output col f = 16wv+cidx), NOT prescaled
    const int  fx  = 16 * wv + cidx;
    const bool fxv = (wv < 2) && (fx < FEAT);
    const int  fxc = fxv ? fx : 0;
    s16x8 bfr_r[4];
    #pragma unroll
    for (int s = 0; s < 4; ++s) {
        s16x8 fr;
        #pragma unroll
        for (int j = 0; j < 8; ++j) {
            int k = 32 * s + 8 * gidx + j;
            fr[j] = (short)to_bf16(fxv ? W_reg[fxc * HID + k] : 0.0f);
        }
        bfr_r[s] = fr;
    }
    const float br_r = fxv ? b_reg[fxc] : 0.0f;
    __syncthreads();   // zero-init visible before prologue panel writes

    // ---------- prologue: staging on waves 2..7 ----------
    const int st  = tid - 128;
    const bool stg = (st >= 0) && (st < BT * FEAT);
    const int rr = stg ? st / FEAT : 0;
    const int ff = stg ? (st - rr * FEAT) : 0;
    const int rowbase = (bbase + rr) * (T_LEN * FEAT) + ff;
    float nx = 0.f, nm = 0.f, nd = 0.f;
    if (stg) {
        float x0 = values[rowbase], m0 = masks[rowbase];
        xm_s[0][rr][ff] = make_float2(x0, m0);
        ak_s[0][rr][160 + ff] = to_bf16(m0);            // m(0) -> panel[0]
        nx = values[rowbase + FEAT];
        nm = masks[rowbase + FEAT];
        nd = deltas[rowbase + FEAT];
    }
    float c_r[4]   = {0.f, 0.f, 0.f, 0.f};
    float h_r[4]   = {0.f, 0.f, 0.f, 0.f};
    float gam_r[4] = {0.f, 0.f, 0.f, 0.f};   // h=0 at t=0 -> value irrelevant
    float xl_acc = 0.0f;
    __syncthreads();

    #pragma unroll 2
    for (int t = 0; t < T_LEN; ++t) {
        const int par = t & 1;

        // ---- P: flush t+1 stages, issue t+2 loads, h_d -> panel[par] ----
        float lx = 0.f, lm = 0.f, ld = 0.f;
        if (stg) {
            d_s[par ^ 1][rr][ff] = to_bf16f(nd);
            xm_s[par ^ 1][rr][ff] = make_float2(nx, nm);
            int idx = (t + 2 < T_LEN) ? (t + 2) : (T_LEN - 1);
            int o = rowbase + idx * FEAT;
            lx = values[o]; lm = masks[o]; ld = deltas[o];
        }
        #pragma unroll
        for (int v = 0; v < 4; ++v)
            ak_s[par][4 * gidx + v][jh] = to_bf16f(h_r[v] * gam_r[v]);
        __syncthreads();                                // bar1

        // ---- Q ----
        s16x8 aF0 = *(const s16x8*)&ak_s[par][cidx][      8 * gidx];
        s16x8 aF1 = *(const s16x8*)&ak_s[par][cidx][ 32 + 8 * gidx];
        s16x8 aF2 = *(const s16x8*)&ak_s[par][cidx][ 64 + 8 * gidx];
        s16x8 aF3 = *(const s16x8*)&ak_s[par][cidx][ 96 + 8 * gidx];
        s16x8 aM  = *(const s16x8*)&ak_s[par][cidx][160 + 8 * gidx];
        s16x8 ad  = *(const s16x8*)&d_s[par ^ 1][cidx][8 * gidx];
        if (stg) {
            ak_s[par ^ 1][rr][160 + ff] = to_bf16f(nm);   // m(t+1)
            if (t > 0) {   // offloaded imp store + loss for step t-1
                float xcp = xc_s[par ^ 1][rr][ff];
                float ep  = bf16_to_f(ak_s[par ^ 1][rr][128 + ff]);
                out_imp[rowbase + (t - 1) * FEAT] = xcp;
                xl_acc += fabsf(ep) * rden_s[t - 1];
            }
        }

        // gate MFMAs, split chains: accA = b + s0,s1,m ; accB = s2,s3 (+e in R)
        f32x4 accA0 = {bs_r[0], bs_r[0], bs_r[0], bs_r[0]};
        f32x4 accA1 = {bs_r[1], bs_r[1], bs_r[1], bs_r[1]};
        f32x4 accA2 = {bs_r[2], bs_r[2], bs_r[2], bs_r[2]};
        f32x4 accA3 = {bs_r[3], bs_r[3], bs_r[3], bs_r[3]};
        f32x4 accB0 = {0.f, 0.f, 0.f, 0.f};
        f32x4 accB1 = {0.f, 0.f, 0.f, 0.f};
        f32x4 accB2 = {0.f, 0.f, 0.f, 0.f};
        f32x4 accB3 = {0.f, 0.f, 0.f, 0.f};
        accA0 = MFMA16(aF0, bfr_g[0][0], accA0); accA1 = MFMA16(aF0, bfr_g[1][0], accA1);
        accA2 = MFMA16(aF0, bfr_g[2][0], accA2); accA3 = MFMA16(aF0, bfr_g[3][0], accA3);
        accB0 = MFMA16(aF2, bfr_g[0][2], accB0); accB1 = MFMA16(aF2, bfr_g[1][2], accB1);
        accB2 = MFMA16(aF2, bfr_g[2][2], accB2); accB3 = MFMA16(aF2, bfr_g[3][2], accB3);
        accA0 = MFMA16(aF1, bfr_g[0][1], accA0); accA1 = MFMA16(aF1, bfr_g[1][1], accA1);
        accA2 = MFMA16(aF1, bfr_g[2][1], accA2); accA3 = MFMA16(aF1, bfr_g[3][1], accA3);
        accB0 = MFMA16(aF3, bfr_g[0][3], accB0); accB1 = MFMA16(aF3, bfr_g[1][3], accB1);
        accB2 = MFMA16(aF3, bfr_g[2][3], accB2); accB3 = MFMA16(aF3, bfr_g[3][3], accB3);
        accA0 = MFMA16(aM, bfr_g[0][5], accA0);  accA1 = MFMA16(aM, bfr_g[1][5], accA1);
        accA2 = MFMA16(aM, bfr_g[2][5], accA2);  accA3 = MFMA16(aM, bfr_g[3][5], accA3);
        f32x4 gacc = {bd_r, bd_r, bd_r, bd_r};
        gacc = MFMA16(ad, bfr_d, gacc);

        if (wv < 2) {
            // xh split 2+2
            f32x4 x1 = {br_r, br_r, br_r, br_r};
            f32x4 x2 = {0.f, 0.f, 0.f, 0.f};
            x1 = MFMA16(aF0, bfr_r[0], x1);
            x2 = MFMA16(aF2, bfr_r[2], x2);
            x1 = MFMA16(aF1, bfr_r[1], x1);
            x2 = MFMA16(aF3, bfr_r[3], x2);
            if (fxv) {
                #pragma unroll
                for (int v = 0; v < 4; ++v) {
                    float xh = x1[v] + x2[v];
                    float2 xm = xm_s[par][4 * gidx + v][fxc];
                    float e  = xm.y * (xm.x - xh);
                    ak_s[par][4 * gidx + v][128 + fxc] = to_bf16f(e);
                    xc_s[par][4 * gidx + v][fxc] = xh + e;
                }
            }
        }
        if (stg) { nx = lx; nm = lm; nd = ld; }
        __syncthreads();                                // bar2

        // ---- R: e-MFMAs (accB) + combine + pointwise ----
        s16x8 aE = *(const s16x8*)&ak_s[par][cidx][128 + 8 * gidx];
        accB0 = MFMA16(aE, bfr_g[0][4], accB0);
        accB1 = MFMA16(aE, bfr_g[1][4], accB1);
        accB2 = MFMA16(aE, bfr_g[2][4], accB2);
        accB3 = MFMA16(aE, bfr_g[3][4], accB3);
        #pragma unroll
        for (int v = 0; v < 4; ++v) {
            float g0 = accA0[v] + accB0[v];
            float g1 = accA1[v] + accB1[v];
            float g2 = accA2[v] + accB2[v];
            float g3 = accA3[v] + accB3[v];
            float ig = rcp_f(1.0f + exp2_f(-g0));
            float fg = rcp_f(1.0f + exp2_f(-g1));
            float gg = 2.0f * rcp_f(1.0f + exp2_f(-g2)) - 1.0f;
            float og = rcp_f(1.0f + exp2_f(-g3));
            c_r[v] = fg * c_r[v] + ig * gg;
            float th = 2.0f * rcp_f(1.0f + exp2_f(-2.0f * LOG2E * c_r[v])) - 1.0f;
            h_r[v] = og * th;
            gam_r[v] = exp2_f(-fmaxf(gacc[v], 0.0f));
        }
        // no barrier: P(t+1) writes are barrier-separated per audit
    }

    // ---------- final imp flush for t = T_LEN-1 (par = 1) ----------
    if (stg) {
        float xcp = xc_s[1][rr][ff];
        float ep  = bf16_to_f(ak_s[1][rr][128 + ff]);
        out_imp[rowbase + (T_LEN - 1) * FEAT] = xcp;
        xl_acc += fabsf(ep) * rden_s[T_LEN - 1];
    }

    // ---------- epilogue ----------
    #pragma unroll
    for (int v = 0; v < 4; ++v) hfin_s[4 * gidx + v][jh] = h_r[v];
    red_s[tid] = xl_acc;
    __syncthreads();
    #pragma unroll
    for (int s = NTHR / 2; s > 0; s >>= 1) {
        if (tid < s) red_s[tid] += red_s[tid + s];
        __syncthreads();
    }
    if (tid == 0) xlpart[blk] = red_s[0];

    float yerr = 0.0f, ytr = 0.0f;
    if (tid < BT) {
        float acc = b_out[0];
        for (int k = 0; k < HID; ++k) acc += W_out[k] * hfin_s[tid][k];
        out_yh[bbase + tid] = acc;
        float it = is_train[bbase + tid];
        float dv = acc - labels[bbase + tid];
        yerr = dv * dv * it;
        ytr  = it;
    }
    #pragma unroll
    for (int s = 8; s > 0; s >>= 1) {
        yerr += __shfl_down(yerr, s);
        ytr  += __shfl_down(ytr, s);
    }
    if (tid == 0) { wsynum[blk] = yerr; wsyden[blk] = ytr; }
}

__global__ __launch_bounds__(256) void rits_final(
    const float* __restrict__ xlpart,
    const float* __restrict__ wsynum, const float* __restrict__ wsyden,
    float* __restrict__ d_out)
{
    __shared__ float sx[256], sy[256], sz[256];
    int tid = threadIdx.x;
    sx[tid] = xlpart[tid];
    sy[tid] = wsynum[tid];
    sz[tid] = wsyden[tid];
    __syncthreads();
    for (int s = 128; s > 0; s >>= 1) {
        if (tid < s) { sx[tid] += sx[tid + s]; sy[tid] += sy[tid + s]; sz[tid] += sz[tid + s]; }
        __syncthreads();
    }
    if (tid == 0) d_out[0] = sx[0] + sy[0] / (sz[0] + 1e-5f);
}

extern "C" void kernel_launch(void* const* d_in, const int* in_sizes, int n_in,
                              void* d_out, int out_size, void* d_ws, size_t ws_size,
                              hipStream_t stream)
{
    const float* values    = (const float*)d_in[0];
    const float* masks     = (const float*)d_in[1];
    const float* deltas    = (const float*)d_in[2];
    // d_in[3] evals, d_in[4] eval_masks : unused
    const float* labels    = (const float*)d_in[5];
    const float* is_train  = (const float*)d_in[6];
    const float* W_decay   = (const float*)d_in[7];
    const float* b_decay   = (const float*)d_in[8];
    const float* W_reg     = (const float*)d_in[9];
    const float* b_reg     = (const float*)d_in[10];
    const float* W_ih      = (const float*)d_in[11];
    const float* W_hh      = (const float*)d_in[12];
    const float* b_ih      = (const float*)d_in[13];
    const float* b_hh      = (const float*)d_in[14];
    const float* W_out     = (const float*)d_in[15];
    const float* b_out     = (const float*)d_in[16];

    float* ws     = (float*)d_ws;
    float* whh2   = ws + WS_WHH2;
    float* rden   = ws + WS_RDEN;
    float* xlpart = ws + WS_XL;
    float* wsynum = ws + WS_YNUM;
    float* wsyden = ws + WS_YDEN;

    float* out     = (float*)d_out;
    float* out_yh  = out + 1;
    float* out_imp = out + 1 + BTOT;

    rits_den<<<dim3(T_LEN), dim3(1024), 0, stream>>>(masks, rden);
    rits_fold<<<dim3(256), dim3(256), 0, stream>>>(W_ih, W_hh, W_reg, whh2);

    rits_main<<<dim3(NB), dim3(NTHR), 0, stream>>>(
        values, masks, deltas, labels, is_train,
        W_decay, b_decay, W_reg, b_reg, W_ih, W_hh, b_ih, b_hh, W_out, b_out,
        whh2, rden, out_yh, out_imp, xlpart, wsynum, wsyden);

    rits_final<<<dim3(1), dim3(256), 0, stream>>>(xlpart, wsynum, wsyden, out);
}